// Round 2
// baseline (8339.053 us; speedup 1.0000x reference)
//
#include <hip/hip_runtime.h>
#include <hip/hip_bf16.h>

typedef __hip_bfloat16 bf16;
typedef __bf16 bf16x8 __attribute__((ext_vector_type(8)));
typedef float f32x4 __attribute__((ext_vector_type(4)));

#define ROWS   32
#define HID    1024
#define PATH   256
#define KIN    1280   // HID + PATH
#define NSTEP  50
#define IP     1288   // inp LDS pitch (bf16 elems): 1280 + 8 pad
#define TP     1032   // th  LDS pitch: 1024 + 8 pad
#define SMEM_BYTES ((ROWS*IP + ROWS*TP) * 2)

__device__ __forceinline__ f32x4 mfma16(bf16x8 a, bf16x8 b, f32x4 c) {
    return __builtin_amdgcn_mfma_f32_16x16x32_bf16(a, b, c, 0, 0, 0);
}

__device__ __forceinline__ float tanh_fast(float x) {
    float e = __expf(2.0f * x);
    return 1.0f - 2.0f / (e + 1.0f);   // saturates to +/-1, no NaN for finite x
}

// load 8 consecutive f32, convert to bf16x8 (RNE)
__device__ __forceinline__ bf16x8 ldcvt8(const float* __restrict__ p) {
    f32x4 lo = *(const f32x4*)p;
    f32x4 hi = *(const f32x4*)(p + 4);
    bf16x8 r;
    #pragma unroll
    for (int j = 0; j < 4; j++) { r[j] = (__bf16)lo[j]; r[4 + j] = (__bf16)hi[j]; }
    return r;
}

// ------------- transpose + downcast: src f32 [K][N] -> dst bf16 [N][K] -------------
__global__ void tpose(const float* __restrict__ src, bf16* __restrict__ dst, int K, int N) {
    __shared__ bf16 t[32][33];
    int n0 = blockIdx.x * 32, k0 = blockIdx.y * 32;
    int tx = threadIdx.x, ty = threadIdx.y;            // (32,8)
    #pragma unroll
    for (int i = 0; i < 32; i += 8)
        t[ty + i][tx] = __float2bfloat16(src[(size_t)(k0 + ty + i) * N + n0 + tx]);
    __syncthreads();
    #pragma unroll
    for (int i = 0; i < 32; i += 8)
        dst[(size_t)(n0 + ty + i) * K + k0 + tx] = t[tx][ty + i];
}

// ---------------- persistent fused CDE kernel ----------------
// 256 wgs (1/CU), 512 threads (8 waves). Each wg owns 32 batch rows; z stays in
// f32 registers in MFMA C-layout across all 50 steps. Wave w computes cols
// [128w,128w+128) of every 1024-col GEMM and cols [32w,32w+32) of the g GEMM.
__global__ __launch_bounds__(512, 2) void cde_main(
    const float* __restrict__ x0,  const float* __restrict__ b_pe, const float* __restrict__ b_hi,
    const float* __restrict__ b1v, const float* __restrict__ b2v,  const float* __restrict__ b_ro,
    const bf16* __restrict__ WpeT, const bf16* __restrict__ WhiT,
    const bf16* __restrict__ W1T,  const bf16* __restrict__ W2T, const bf16* __restrict__ WroT,
    float* __restrict__ out)
{
    extern __shared__ bf16 smem[];
    bf16* inp = smem;              // [32][IP]  cols 0..1023 = z, 1024..1279 = u_t
    bf16* th  = smem + ROWS * IP;  // [32][TP]

    const int tid  = threadIdx.x;
    const int wave = tid >> 6;
    const int lane = tid & 63;
    const int lm   = lane & 15;    // A/B frag m|n; C/D col
    const int lq   = lane >> 4;    // k-quad;     C/D row = lq*4 + reg
    const long row0 = (long)blockIdx.x * ROWS;

    f32x4 z[2][8];   // persistent z: row = mt*16+lq*4+r, col = wave*128+nt*16+lm
    f32x4 g[2][2];   // persistent g: col = wave*32+nt*16+lm

    // ---- merged prologue: g = x0@W_pe + b_pe ; z = x0@W_hi + b_hi ----
    #pragma unroll
    for (int nt = 0; nt < 8; nt++) {
        float b = b_hi[wave * 128 + nt * 16 + lm];
        #pragma unroll
        for (int r = 0; r < 4; r++) { z[0][nt][r] = b; z[1][nt][r] = b; }
    }
    #pragma unroll
    for (int nt = 0; nt < 2; nt++) {
        float b = b_pe[wave * 32 + nt * 16 + lm];
        #pragma unroll
        for (int r = 0; r < 4; r++) { g[0][nt][r] = b; g[1][nt][r] = b; }
    }
    for (int k0 = 0; k0 < HID; k0 += 32) {
        bf16x8 a0 = ldcvt8(x0 + (row0 +      lm) * HID + k0 + lq * 8);
        bf16x8 a1 = ldcvt8(x0 + (row0 + 16 + lm) * HID + k0 + lq * 8);
        #pragma unroll
        for (int nt = 0; nt < 8; nt++) {
            bf16x8 bb = *(const bf16x8*)(WhiT + (size_t)(wave * 128 + nt * 16 + lm) * HID + k0 + lq * 8);
            z[0][nt] = mfma16(a0, bb, z[0][nt]);
            z[1][nt] = mfma16(a1, bb, z[1][nt]);
        }
        #pragma unroll
        for (int nt = 0; nt < 2; nt++) {
            bf16x8 bb = *(const bf16x8*)(WpeT + (size_t)(wave * 32 + nt * 16 + lm) * HID + k0 + lq * 8);
            g[0][nt] = mfma16(a0, bb, g[0][nt]);
            g[1][nt] = mfma16(a1, bb, g[1][nt]);
        }
    }

    const float DT = 1.0f / (float)NSTEP;

    // ---- 50 fused steps ----
    for (int s = 0; s < NSTEP; s++) {
        float t = DT * (float)(s + 1);

        // A-phase: refresh bf16 inp = [z | t*g] from registers
        #pragma unroll
        for (int mt = 0; mt < 2; mt++)
            #pragma unroll
            for (int nt = 0; nt < 8; nt++)
                #pragma unroll
                for (int r = 0; r < 4; r++)
                    inp[(mt * 16 + lq * 4 + r) * IP + wave * 128 + nt * 16 + lm] =
                        __float2bfloat16(z[mt][nt][r]);
        #pragma unroll
        for (int mt = 0; mt < 2; mt++)
            #pragma unroll
            for (int nt = 0; nt < 2; nt++)
                #pragma unroll
                for (int r = 0; r < 4; r++)
                    inp[(mt * 16 + lq * 4 + r) * IP + HID + wave * 32 + nt * 16 + lm] =
                        __float2bfloat16(t * g[mt][nt][r]);
        __syncthreads();

        // B-phase: h = tanh(inp @ W1 + b1) -> th
        {
            f32x4 acc[2][8];
            #pragma unroll
            for (int nt = 0; nt < 8; nt++) {
                float b = b1v[wave * 128 + nt * 16 + lm];
                #pragma unroll
                for (int r = 0; r < 4; r++) { acc[0][nt][r] = b; acc[1][nt][r] = b; }
            }
            #pragma unroll 2
            for (int k0 = 0; k0 < KIN; k0 += 32) {
                bf16x8 a0 = *(const bf16x8*)(inp + (     lm) * IP + k0 + lq * 8);
                bf16x8 a1 = *(const bf16x8*)(inp + (16 + lm) * IP + k0 + lq * 8);
                #pragma unroll
                for (int nt = 0; nt < 8; nt++) {
                    bf16x8 bb = *(const bf16x8*)(W1T + (size_t)(wave * 128 + nt * 16 + lm) * KIN + k0 + lq * 8);
                    acc[0][nt] = mfma16(a0, bb, acc[0][nt]);
                    acc[1][nt] = mfma16(a1, bb, acc[1][nt]);
                }
            }
            #pragma unroll
            for (int mt = 0; mt < 2; mt++)
                #pragma unroll
                for (int nt = 0; nt < 8; nt++)
                    #pragma unroll
                    for (int r = 0; r < 4; r++)
                        th[(mt * 16 + lq * 4 + r) * TP + wave * 128 + nt * 16 + lm] =
                            __float2bfloat16(tanh_fast(acc[mt][nt][r]));
        }
        __syncthreads();

        // C-phase: dz = th @ W2 + b2 ; z += dt*dz
        {
            f32x4 acc[2][8];
            #pragma unroll
            for (int nt = 0; nt < 8; nt++) {
                float b = b2v[wave * 128 + nt * 16 + lm];
                #pragma unroll
                for (int r = 0; r < 4; r++) { acc[0][nt][r] = b; acc[1][nt][r] = b; }
            }
            #pragma unroll 2
            for (int k0 = 0; k0 < HID; k0 += 32) {
                bf16x8 a0 = *(const bf16x8*)(th + (     lm) * TP + k0 + lq * 8);
                bf16x8 a1 = *(const bf16x8*)(th + (16 + lm) * TP + k0 + lq * 8);
                #pragma unroll
                for (int nt = 0; nt < 8; nt++) {
                    bf16x8 bb = *(const bf16x8*)(W2T + (size_t)(wave * 128 + nt * 16 + lm) * HID + k0 + lq * 8);
                    acc[0][nt] = mfma16(a0, bb, acc[0][nt]);
                    acc[1][nt] = mfma16(a1, bb, acc[1][nt]);
                }
            }
            #pragma unroll
            for (int mt = 0; mt < 2; mt++)
                #pragma unroll
                for (int nt = 0; nt < 8; nt++)
                    #pragma unroll
                    for (int r = 0; r < 4; r++)
                        z[mt][nt][r] += DT * acc[mt][nt][r];
        }
        // no barrier needed: next A-phase touches inp only; th write/read pairs are
        // separated by barrier (1) of the next iteration.
    }

    // ---- epilogue: out = z @ W_ro + b_ro (f32 store) ----
    #pragma unroll
    for (int mt = 0; mt < 2; mt++)
        #pragma unroll
        for (int nt = 0; nt < 8; nt++)
            #pragma unroll
            for (int r = 0; r < 4; r++)
                inp[(mt * 16 + lq * 4 + r) * IP + wave * 128 + nt * 16 + lm] =
                    __float2bfloat16(z[mt][nt][r]);
    __syncthreads();
    {
        f32x4 acc[2][8];
        #pragma unroll
        for (int nt = 0; nt < 8; nt++) {
            float b = b_ro[wave * 128 + nt * 16 + lm];
            #pragma unroll
            for (int r = 0; r < 4; r++) { acc[0][nt][r] = b; acc[1][nt][r] = b; }
        }
        #pragma unroll 2
        for (int k0 = 0; k0 < HID; k0 += 32) {
            bf16x8 a0 = *(const bf16x8*)(inp + (     lm) * IP + k0 + lq * 8);
            bf16x8 a1 = *(const bf16x8*)(inp + (16 + lm) * IP + k0 + lq * 8);
            #pragma unroll
            for (int nt = 0; nt < 8; nt++) {
                bf16x8 bb = *(const bf16x8*)(WroT + (size_t)(wave * 128 + nt * 16 + lm) * HID + k0 + lq * 8);
                acc[0][nt] = mfma16(a0, bb, acc[0][nt]);
                acc[1][nt] = mfma16(a1, bb, acc[1][nt]);
            }
        }
        #pragma unroll
        for (int mt = 0; mt < 2; mt++)
            #pragma unroll
            for (int nt = 0; nt < 8; nt++)
                #pragma unroll
                for (int r = 0; r < 4; r++)
                    out[(row0 + mt * 16 + lq * 4 + r) * HID + wave * 128 + nt * 16 + lm] =
                        acc[mt][nt][r];
    }
}

extern "C" void kernel_launch(void* const* d_in, const int* in_sizes, int n_in,
                              void* d_out, int out_size, void* d_ws, size_t ws_size,
                              hipStream_t stream) {
    (void)in_sizes; (void)n_in; (void)out_size; (void)ws_size;
    const float* x0  = (const float*)d_in[0];
    const float* Wpe = (const float*)d_in[1];
    const float* bpe = (const float*)d_in[2];
    const float* Whi = (const float*)d_in[3];
    const float* bhi = (const float*)d_in[4];
    const float* W1  = (const float*)d_in[5];
    const float* b1  = (const float*)d_in[6];
    const float* W2  = (const float*)d_in[7];
    const float* b2  = (const float*)d_in[8];
    const float* Wro = (const float*)d_in[9];
    const float* bro = (const float*)d_in[10];

    bf16* ws   = (bf16*)d_ws;
    bf16* WpeT = ws;                         // [256][1024]
    bf16* WhiT = WpeT + 256 * 1024;          // [1024][1024]
    bf16* W1T  = WhiT + 1024 * 1024;         // [1024][1280]
    bf16* W2T  = W1T  + 1024 * 1280;         // [1024][1024]
    bf16* WroT = W2T  + 1024 * 1024;         // [1024][1024]

    dim3 tb(32, 8);
    hipLaunchKernelGGL(tpose, dim3(256 / 32, 1024 / 32), tb, 0, stream, Wpe, WpeT, 1024, 256);
    hipLaunchKernelGGL(tpose, dim3(1024 / 32, 1024 / 32), tb, 0, stream, Whi, WhiT, 1024, 1024);
    hipLaunchKernelGGL(tpose, dim3(1024 / 32, 1280 / 32), tb, 0, stream, W1, W1T, 1280, 1024);
    hipLaunchKernelGGL(tpose, dim3(1024 / 32, 1024 / 32), tb, 0, stream, W2, W2T, 1024, 1024);
    hipLaunchKernelGGL(tpose, dim3(1024 / 32, 1024 / 32), tb, 0, stream, Wro, WroT, 1024, 1024);

    hipFuncSetAttribute((const void*)cde_main,
                        hipFuncAttributeMaxDynamicSharedMemorySize, SMEM_BYTES);
    hipLaunchKernelGGL(cde_main, dim3(8192 / ROWS), dim3(512), SMEM_BYTES, stream,
                       x0, bpe, bhi, b1, b2, bro, WpeT, WhiT, W1T, W2T, WroT,
                       (float*)d_out);
}

// Round 3
// 4859.304 us; speedup vs baseline: 1.7161x; 1.7161x over previous
//
#include <hip/hip_runtime.h>
#include <hip/hip_bf16.h>

typedef __hip_bfloat16 bf16;
typedef __bf16 bf16x8 __attribute__((ext_vector_type(8)));
typedef float f32x4 __attribute__((ext_vector_type(4)));

#define ROWS   32
#define HID    1024
#define PATH   256
#define KIN    1280   // HID + PATH
#define NSTEP  50
#define IP     1288   // inp LDS pitch (bf16): 1280 + 8 pad
#define TP     1032   // th  LDS pitch: 1024 + 8 pad
#define SMEM_BYTES ((ROWS*IP + ROWS*TP) * 2)

__device__ __forceinline__ f32x4 mfma16(bf16x8 a, bf16x8 b, f32x4 c) {
    return __builtin_amdgcn_mfma_f32_16x16x32_bf16(a, b, c, 0, 0, 0);
}

__device__ __forceinline__ float tanh_fast(float x) {
    float e = __expf(2.0f * x);
    return 1.0f - 2.0f / (e + 1.0f);   // saturates, no NaN for finite x
}

__device__ __forceinline__ bf16x8 ldcvt8(const float* __restrict__ p) {
    f32x4 lo = *(const f32x4*)p;
    f32x4 hi = *(const f32x4*)(p + 4);
    bf16x8 r;
    #pragma unroll
    for (int j = 0; j < 4; j++) { r[j] = (__bf16)lo[j]; r[4 + j] = (__bf16)hi[j]; }
    return r;
}

// ---- pack f32 W[K][N] into bf16 MFMA B-fragment-linear layout ----
// fragment (kb, nb) = 1KB: lane l (lm=l&15, lq=l>>4) holds W[kb*32+lq*8+j][nb*16+lm], j=0..7
// dst elem index: ((kb * (N/16) + nb) * 64 + l) * 8 + j
__global__ void pack_frag(const float* __restrict__ src, bf16* __restrict__ dst, int N) {
    int kb = blockIdx.x, nb = blockIdx.y, l = threadIdx.x;
    int lm = l & 15, lq = l >> 4;
    bf16x8 v;
    #pragma unroll
    for (int j = 0; j < 8; j++)
        v[j] = __float2bfloat16(src[(size_t)(kb * 32 + lq * 8 + j) * N + nb * 16 + lm]);
    *(bf16x8*)(dst + ((size_t)(kb * gridDim.y + nb) * 64 + l) * 8) = v;
}

// ---- one 32xN=1024 GEMM phase: acc[2][8] += lds_A(32 rows) @ Wp(packed), KB k-blocks ----
template<int KB>
__device__ __forceinline__ void gemm8(const bf16* __restrict__ lds, int pitch,
                                      const bf16* __restrict__ Wp,
                                      int wave, int lane, f32x4 (&acc)[2][8]) {
    const int lm = lane & 15, lq = lane >> 4;
    #pragma unroll 2
    for (int kb = 0; kb < KB; kb++) {
        const bf16* wp = Wp + (((size_t)kb * 64 + wave * 8) * 64 + lane) * 8;
        bf16x8 w[8];
        #pragma unroll
        for (int nt = 0; nt < 8; nt++) w[nt] = *(const bf16x8*)(wp + nt * 512);
        bf16x8 a0 = *(const bf16x8*)(lds + lm * pitch + kb * 32 + lq * 8);
        bf16x8 a1 = *(const bf16x8*)(lds + (16 + lm) * pitch + kb * 32 + lq * 8);
        #pragma unroll
        for (int nt = 0; nt < 8; nt++) {
            acc[0][nt] = mfma16(a0, w[nt], acc[0][nt]);
            acc[1][nt] = mfma16(a1, w[nt], acc[1][nt]);
        }
    }
}

// ---------------- persistent fused CDE kernel ----------------
// 256 wgs (1/CU), 512 threads (8 waves). Each wg owns 32 batch rows; z persists in
// f32 registers in MFMA C-layout. Wave w computes cols [128w,128w+128) of the
// 1024-col GEMMs and cols [32w,32w+32) of the 256-col g GEMM.
__global__ __launch_bounds__(512, 2) void cde_main(
    const float* __restrict__ x0,  const float* __restrict__ b_pe, const float* __restrict__ b_hi,
    const float* __restrict__ b1v, const float* __restrict__ b2v,  const float* __restrict__ b_ro,
    const bf16* __restrict__ WpeP, const bf16* __restrict__ WhiP,
    const bf16* __restrict__ W1P,  const bf16* __restrict__ W2P, const bf16* __restrict__ WroP,
    float* __restrict__ out)
{
    extern __shared__ bf16 smem[];
    bf16* inp = smem;              // [32][IP]  cols 0..1023 = z, 1024..1279 = u_t
    bf16* th  = smem + ROWS * IP;  // [32][TP]

    const int tid  = threadIdx.x;
    const int wave = tid >> 6;
    const int lane = tid & 63;
    const int lm   = lane & 15;
    const int lq   = lane >> 4;
    const long row0 = (long)blockIdx.x * ROWS;

    f32x4 z[2][8];   // row = mt*16+lq*4+r, col = wave*128+nt*16+lm
    f32x4 g[2][2];   // col = wave*32+nt*16+lm

    // ---- merged prologue: g = x0@W_pe + b_pe ; z = x0@W_hi + b_hi ----
    #pragma unroll
    for (int nt = 0; nt < 8; nt++) {
        float b = b_hi[wave * 128 + nt * 16 + lm];
        #pragma unroll
        for (int r = 0; r < 4; r++) { z[0][nt][r] = b; z[1][nt][r] = b; }
    }
    #pragma unroll
    for (int nt = 0; nt < 2; nt++) {
        float b = b_pe[wave * 32 + nt * 16 + lm];
        #pragma unroll
        for (int r = 0; r < 4; r++) { g[0][nt][r] = b; g[1][nt][r] = b; }
    }
    for (int kb = 0; kb < HID / 32; kb++) {
        bf16x8 a0 = ldcvt8(x0 + (row0 +      lm) * HID + kb * 32 + lq * 8);
        bf16x8 a1 = ldcvt8(x0 + (row0 + 16 + lm) * HID + kb * 32 + lq * 8);
        const bf16* wp = WhiP + (((size_t)kb * 64 + wave * 8) * 64 + lane) * 8;
        #pragma unroll
        for (int nt = 0; nt < 8; nt++) {
            bf16x8 bb = *(const bf16x8*)(wp + nt * 512);
            z[0][nt] = mfma16(a0, bb, z[0][nt]);
            z[1][nt] = mfma16(a1, bb, z[1][nt]);
        }
        const bf16* pp = WpeP + (((size_t)kb * 16 + wave * 2) * 64 + lane) * 8;
        #pragma unroll
        for (int nt = 0; nt < 2; nt++) {
            bf16x8 bb = *(const bf16x8*)(pp + nt * 512);
            g[0][nt] = mfma16(a0, bb, g[0][nt]);
            g[1][nt] = mfma16(a1, bb, g[1][nt]);
        }
    }

    const float DT = 1.0f / (float)NSTEP;

    // ---- 50 fused steps ----
    for (int s = 0; s < NSTEP; s++) {
        float t = DT * (float)(s + 1);

        // A-phase: refresh bf16 inp = [z | t*g] from registers
        #pragma unroll
        for (int mt = 0; mt < 2; mt++)
            #pragma unroll
            for (int nt = 0; nt < 8; nt++)
                #pragma unroll
                for (int r = 0; r < 4; r++)
                    inp[(mt * 16 + lq * 4 + r) * IP + wave * 128 + nt * 16 + lm] =
                        __float2bfloat16(z[mt][nt][r]);
        #pragma unroll
        for (int mt = 0; mt < 2; mt++)
            #pragma unroll
            for (int nt = 0; nt < 2; nt++)
                #pragma unroll
                for (int r = 0; r < 4; r++)
                    inp[(mt * 16 + lq * 4 + r) * IP + HID + wave * 32 + nt * 16 + lm] =
                        __float2bfloat16(t * g[mt][nt][r]);
        __syncthreads();

        // B-phase: h = tanh(inp @ W1 + b1) -> th
        {
            f32x4 acc[2][8];
            #pragma unroll
            for (int nt = 0; nt < 8; nt++) {
                float b = b1v[wave * 128 + nt * 16 + lm];
                #pragma unroll
                for (int r = 0; r < 4; r++) { acc[0][nt][r] = b; acc[1][nt][r] = b; }
            }
            gemm8<KIN / 32>(inp, IP, W1P, wave, lane, acc);
            #pragma unroll
            for (int mt = 0; mt < 2; mt++)
                #pragma unroll
                for (int nt = 0; nt < 8; nt++)
                    #pragma unroll
                    for (int r = 0; r < 4; r++)
                        th[(mt * 16 + lq * 4 + r) * TP + wave * 128 + nt * 16 + lm] =
                            __float2bfloat16(tanh_fast(acc[mt][nt][r]));
        }
        __syncthreads();

        // C-phase: dz = th @ W2 + b2 ; z += dt*dz
        {
            f32x4 acc[2][8];
            #pragma unroll
            for (int nt = 0; nt < 8; nt++) {
                float b = b2v[wave * 128 + nt * 16 + lm];
                #pragma unroll
                for (int r = 0; r < 4; r++) { acc[0][nt][r] = b; acc[1][nt][r] = b; }
            }
            gemm8<HID / 32>(th, TP, W2P, wave, lane, acc);
            #pragma unroll
            for (int mt = 0; mt < 2; mt++)
                #pragma unroll
                for (int nt = 0; nt < 8; nt++)
                    #pragma unroll
                    for (int r = 0; r < 4; r++)
                        z[mt][nt][r] += DT * acc[mt][nt][r];
        }
        // no barrier here: next A-phase writes inp only; th hazards are separated by
        // the A->B barrier of the next iteration.
    }

    // ---- epilogue: out = z @ W_ro + b_ro (f32 store) ----
    #pragma unroll
    for (int mt = 0; mt < 2; mt++)
        #pragma unroll
        for (int nt = 0; nt < 8; nt++)
            #pragma unroll
            for (int r = 0; r < 4; r++)
                inp[(mt * 16 + lq * 4 + r) * IP + wave * 128 + nt * 16 + lm] =
                    __float2bfloat16(z[mt][nt][r]);
    __syncthreads();
    {
        f32x4 acc[2][8];
        #pragma unroll
        for (int nt = 0; nt < 8; nt++) {
            float b = b_ro[wave * 128 + nt * 16 + lm];
            #pragma unroll
            for (int r = 0; r < 4; r++) { acc[0][nt][r] = b; acc[1][nt][r] = b; }
        }
        gemm8<HID / 32>(inp, IP, WroP, wave, lane, acc);
        #pragma unroll
        for (int mt = 0; mt < 2; mt++)
            #pragma unroll
            for (int nt = 0; nt < 8; nt++)
                #pragma unroll
                for (int r = 0; r < 4; r++)
                    out[(row0 + mt * 16 + lq * 4 + r) * HID + wave * 128 + nt * 16 + lm] =
                        acc[mt][nt][r];
    }
}

extern "C" void kernel_launch(void* const* d_in, const int* in_sizes, int n_in,
                              void* d_out, int out_size, void* d_ws, size_t ws_size,
                              hipStream_t stream) {
    (void)in_sizes; (void)n_in; (void)out_size; (void)ws_size;
    const float* x0  = (const float*)d_in[0];
    const float* Wpe = (const float*)d_in[1];
    const float* bpe = (const float*)d_in[2];
    const float* Whi = (const float*)d_in[3];
    const float* bhi = (const float*)d_in[4];
    const float* W1  = (const float*)d_in[5];
    const float* b1  = (const float*)d_in[6];
    const float* W2  = (const float*)d_in[7];
    const float* b2  = (const float*)d_in[8];
    const float* Wro = (const float*)d_in[9];
    const float* bro = (const float*)d_in[10];

    bf16* ws   = (bf16*)d_ws;
    bf16* WpeP = ws;                         // 256*1024
    bf16* WhiP = WpeP + 256 * 1024;          // 1024*1024
    bf16* W1P  = WhiP + 1024 * 1024;         // 1280*1024
    bf16* W2P  = W1P  + 1280 * 1024;         // 1024*1024
    bf16* WroP = W2P  + 1024 * 1024;         // 1024*1024

    hipLaunchKernelGGL(pack_frag, dim3(1024 / 32, 256 / 16), dim3(64), 0, stream, Wpe, WpeP, 256);
    hipLaunchKernelGGL(pack_frag, dim3(1024 / 32, 1024 / 16), dim3(64), 0, stream, Whi, WhiP, 1024);
    hipLaunchKernelGGL(pack_frag, dim3(1280 / 32, 1024 / 16), dim3(64), 0, stream, W1, W1P, 1024);
    hipLaunchKernelGGL(pack_frag, dim3(1024 / 32, 1024 / 16), dim3(64), 0, stream, W2, W2P, 1024);
    hipLaunchKernelGGL(pack_frag, dim3(1024 / 32, 1024 / 16), dim3(64), 0, stream, Wro, WroP, 1024);

    hipFuncSetAttribute((const void*)cde_main,
                        hipFuncAttributeMaxDynamicSharedMemorySize, SMEM_BYTES);
    hipLaunchKernelGGL(cde_main, dim3(8192 / ROWS), dim3(512), SMEM_BYTES, stream,
                       x0, bpe, bhi, b1, b2, bro, WpeP, WhiP, W1P, W2P, WroP,
                       (float*)d_out);
}